// Round 14
// baseline (303.229 us; speedup 1.0000x reference)
//
#include <hip/hip_runtime.h>

typedef unsigned short ushort_t;
typedef unsigned int uint32;
typedef __bf16 bf16x8 __attribute__((ext_vector_type(8)));
typedef float f32x4 __attribute__((ext_vector_type(4)));

#define NTOK 128
#define DIMX 180
#define NH 6
#define HD 30
#define NWIN 64
#define LOG2E 1.4426950408889634f
#define QSCALE (0.18257418583505536f * LOG2E)   // 1/sqrt(30) * log2(e)

__device__ __forceinline__ ushort_t f2bf(float f){
  uint32 u = __float_as_uint(f);
  u += 0x7FFFu + ((u >> 16) & 1u);
  return (ushort_t)(u >> 16);
}
__device__ __forceinline__ uint32 cvt_pk_bf16(float lo, float hi){
  uint32 r;
  asm("v_cvt_pk_bf16_f32 %0, %1, %2" : "=v"(r) : "v"(lo), "v"(hi));
  return r;
}
__device__ __forceinline__ f32x4 mfma16(bf16x8 a, bf16x8 b, f32x4 c){
  return __builtin_amdgcn_mfma_f32_16x16x32_bf16(a, b, c, 0, 0, 0);
}

// ---------------- prep kernels ----------------

// x f32 [131072][180] -> xbf bf16 [131072][192] (pad cols 180..191 = 0)
// grid 6144 x 512: one b128 chunk per thread (131072*24 chunks exactly).
__global__ void prep_x(const float* __restrict__ x, ushort_t* __restrict__ o){
  int g = blockIdx.x*512 + threadIdx.x;
  int row = g / 24, seg = g % 24;
  int k0 = seg*8;
  const float* xr = x + (size_t)row*DIMX + k0;
  float4 fa = {0.f,0.f,0.f,0.f}, fb = {0.f,0.f,0.f,0.f};
  if (k0 + 3 < DIMX) fa = *reinterpret_cast<const float4*>(xr);
  if (k0 + 7 < DIMX) fb = *reinterpret_cast<const float4*>(xr + 4);
  uint4 uu = { cvt_pk_bf16(fa.x, fa.y), cvt_pk_bf16(fa.z, fa.w),
               cvt_pk_bf16(fb.x, fb.y), cvt_pk_bf16(fb.z, fb.w) };
  *reinterpret_cast<uint4*>(&o[(size_t)g*8]) = uu;
}

// wqkvP fragment-contiguous: ((ct_g*6+ks)*64 + lane)*8 + e ; Q-segment pre-scaled
__global__ void prep_wqkv(const float* __restrict__ w, ushort_t* __restrict__ o){
  int blk = blockIdx.x;               // ct_g*6 + ks, 216 blocks
  int ct_g = blk / 6, ks = blk - ct_g*6;
  int lane = threadIdx.x;             // 64
  int l16 = lane & 15, lq = lane >> 4;
  int oc = ct_g*16 + l16;
  int seg = oc >> 5, dd = oc & 31;
  int sel = seg / NH, head = seg % NH;
  ushort_t vals[8];
  #pragma unroll
  for (int e = 0; e < 8; e++){
    int k = ks*32 + lq*8 + e;
    float v = 0.f;
    if (dd < HD && k < DIMX) v = w[k*(3*DIMX) + sel*DIMX + head*HD + dd];
    if (sel == 0) v *= QSCALE;
    vals[e] = f2bf(v);
  }
  *reinterpret_cast<uint4*>(&o[((size_t)blk*64 + lane)*8]) =
      *reinterpret_cast<const uint4*>(vals);
}

// wfcP fragment-contiguous; K positions pair-interleaved to match aoW layout:
// pos p in [0,32) holds original d = (p>>1) + (p&1)*16
__global__ void prep_wfc(const float* __restrict__ w, ushort_t* __restrict__ o){
  int blk = blockIdx.x;               // ct_g*6 + ks, 72 blocks
  int ct_g = blk / 6, ks = blk - ct_g*6;
  int lane = threadIdx.x;
  int l16 = lane & 15, lq = lane >> 4;
  int oc = ct_g*16 + l16;
  ushort_t vals[8];
  #pragma unroll
  for (int e = 0; e < 8; e++){
    int k = ks*32 + lq*8 + e;
    int hh = k >> 5, pos = k & 31;
    int d = (pos >> 1) + (pos & 1)*16;
    float v = (d < HD && oc < DIMX) ? w[(hh*HD + d)*DIMX + oc] : 0.f;
    vals[e] = f2bf(v);
  }
  *reinterpret_cast<uint4*>(&o[((size_t)blk*64 + lane)*8]) =
      *reinterpret_cast<const uint4*>(vals);
}

// bias_p in MFMA C-fragment order, pre-multiplied by log2(e)
__global__ void prep_bias(const float* __restrict__ rpt, const float* __restrict__ mask,
                          const int* __restrict__ rpi, ushort_t* __restrict__ o){
  int blk = blockIdx.x;            // (w*6+h)*8 + wave
  int wave = blk & 7, wh = blk >> 3;
  int h = wh % NH, w = wh / NH;
  int i = threadIdx.x;             // 512
  int lane = i >> 3, t = i & 7;
  int l16 = lane & 15, lq = lane >> 4;
  int m = t*16 + l16;
  ushort_t vals[4];
  #pragma unroll
  for (int r = 0; r < 4; r++){
    int n = wave*16 + lq*4 + r;
    float v = rpt[rpi[n*NTOK + m]*NH + h] + mask[((size_t)w*NTOK + n)*NTOK + m];
    vals[r] = f2bf(v * LOG2E);
  }
  *reinterpret_cast<uint2*>(&o[((size_t)blk*64 + lane)*32 + t*4]) =
      *reinterpret_cast<const uint2*>(vals);
}

// ---------------- fully fused: QKV + attention + FC, one block per window ----------------
// grid 1024, 512 thr, 8 waves x 16 token-rows each.
// LDS 28160 B: k_s [128][36]=4608 @0; v_s [32][136]=4352 @4608; p_s 8x[16][40]=5120 @8960.
// A-frags (x) and B-frags (weights) both read directly from L2/L3-resident packed
// buffers — no xf register array, no ws staging. Target <=64 unified regs -> 4 blocks/CU.
__global__ __launch_bounds__(512, 8) void fused_kernel(
    const ushort_t* __restrict__ xbf, const ushort_t* __restrict__ wqkvP,
    const float* __restrict__ b_qkv, const ushort_t* __restrict__ bias_p,
    ushort_t* __restrict__ aoW, const ushort_t* __restrict__ wfcP,
    const float* __restrict__ b_fc, float* __restrict__ out)
{
  __shared__ ushort_t sm[14080];
  ushort_t* k_s = sm;            // [128 tok][36]
  ushort_t* v_s = sm + 4608;     // [32 d][136]  (token pos pair-interleaved)
  ushort_t* p_s = sm + 8960;     // 8 x [16][40]

  const int tid = threadIdx.x;
  const int b = blockIdx.x;
  const int wk = b & (NWIN-1);
  const int wave = tid >> 6, lane = tid & 63;
  const int l16 = lane & 15, lq = lane >> 4;
  const int wbase = wave * 16;
  ushort_t* pw = p_s + wave*640;
  uint32*   pwu = reinterpret_cast<uint32*>(pw);
  const ushort_t* xrow = xbf + ((size_t)b*NTOK + wbase + l16)*192 + lq*8;

  for (int h = 0; h < NH; h++){
    // QKV accumulators C-initialized with bias (Q pre-scaled)
    f32x4 acc[6];
    #pragma unroll
    for (int ct = 0; ct < 6; ct++){
      const int sel = ct >> 1;
      const int d = (ct & 1)*16 + l16;
      float bc = (d < HD) ? b_qkv[sel*DIMX + h*HD + d] : 0.f;
      if (sel == 0) bc *= QSCALE;
      acc[ct] = f32x4{bc, bc, bc, bc};
    }
    __syncthreads();   // prev head's k_s/v_s reads done

    // ---- QKV for head h: A-frags from xbf, B-frags from wqkvP (both L2-hot) ----
    #pragma unroll
    for (int ks = 0; ks < 6; ks++){
      bf16x8 xk = *reinterpret_cast<const bf16x8*>(xrow + ks*32);
      #pragma unroll
      for (int ct = 0; ct < 6; ct++){
        const int ct_g = ((ct >> 1)*NH + h)*2 + (ct & 1);
        bf16x8 bw = *reinterpret_cast<const bf16x8*>(
            wqkvP + ((size_t)(ct_g*6 + ks)*64 + lane)*8);
        acc[ct] = mfma16(xk, bw, acc[ct]);
      }
    }

    // ---- epilogue: Q -> pw, K -> k_s, V -> v_s (interleaved token pos) ----
    #pragma unroll
    for (int hf = 0; hf < 2; hf++){
      const int d = hf*16 + l16;
      #pragma unroll
      for (int r = 0; r < 4; r++){
        const int tok = wbase + lq*4 + r;
        pw[(lq*4 + r)*40 + d] = f2bf(acc[0 + hf][r]);          // Q (own rows)
        k_s[tok*36 + d]       = f2bf(acc[2 + hf][r]);          // K
        const int tp = (tok & 96) + ((tok & 15) << 1) + ((tok >> 4) & 1);
        v_s[d*136 + tp]       = f2bf(acc[4 + hf][r]);          // V^T
      }
    }

    // bias fragment (latency hides under barrier + QK^T LDS reads)
    bf16x8 bb[4];
    {
      const ushort_t* bp = bias_p + (((size_t)(wk*NH + h)*8 + wave)*64 + lane)*32;
      #pragma unroll
      for (int c = 0; c < 4; c++) bb[c] = *reinterpret_cast<const bf16x8*>(bp + c*8);
    }
    __syncthreads();   // k_s, v_s visible to all waves

    // ---- QK^T with bias C-init ----
    bf16x8 aq = *reinterpret_cast<const bf16x8*>(&pw[l16*40 + lq*8]);
    f32x4 s[8];
    #pragma unroll
    for (int c = 0; c < 4; c++)
      #pragma unroll
      for (int r = 0; r < 4; r++){
        s[2*c][r]   = (float)bb[c][r];
        s[2*c+1][r] = (float)bb[c][4+r];
      }
    #pragma unroll
    for (int t = 0; t < 8; t++){
      bf16x8 bk = *reinterpret_cast<const bf16x8*>(&k_s[(t*16 + l16)*36 + lq*8]);
      s[t] = mfma16(aq, bk, s[t]);
    }

    // ---- softmax: exp2 direct, deferred normalization ----
    float inv[4];
    #pragma unroll
    for (int r = 0; r < 4; r++){
      float sum = 0.f;
      #pragma unroll
      for (int t = 0; t < 8; t++){
        float e = __builtin_exp2f(s[t][r]);
        s[t][r] = e; sum += e;
      }
      #pragma unroll
      for (int off = 1; off < 16; off <<= 1) sum += __shfl_xor(sum, off);
      inv[r] = __builtin_amdgcn_rcpf(sum);
    }

    // ---- PV in 4 k-quarters; P packed via cvt_pk (pair-interleaved tokens) ----
    f32x4 po[2] = { f32x4{0.f,0.f,0.f,0.f}, f32x4{0.f,0.f,0.f,0.f} };
    #pragma unroll
    for (int q = 0; q < 4; q++){
      #pragma unroll
      for (int r = 0; r < 4; r++)
        pwu[(lq*4 + r)*20 + l16] = cvt_pk_bf16(s[2*q][r], s[2*q+1][r]);
      bf16x8 ap = *reinterpret_cast<const bf16x8*>(&pw[l16*40 + lq*8]);
      #pragma unroll
      for (int ct = 0; ct < 2; ct++){
        bf16x8 bv = *reinterpret_cast<const bf16x8*>(&v_s[(ct*16 + l16)*136 + q*32 + lq*8]);
        po[ct] = mfma16(ap, bv, po[ct]);
      }
    }

    // normalize + pack po (d pair-interleaved) -> pw -> coalesced 1KB/wave store
    #pragma unroll
    for (int r = 0; r < 4; r++)
      pwu[(lq*4 + r)*20 + l16] = cvt_pk_bf16(po[0][r]*inv[r], po[1][r]*inv[r]);
    {
      bf16x8 vv = *reinterpret_cast<const bf16x8*>(&pw[(lane>>2)*40 + (lane&3)*8]);
      *reinterpret_cast<bf16x8*>(
        aoW + (((size_t)b*NH + h)*NTOK + wbase + (lane>>2))*32 + (lane&3)*8) = vv;
    }
  }

  // ---- phase 2: FC for this block's 128 rows (two 64-row passes) ----
  __syncthreads();                 // all LDS reads done; aoW stores drained
  ushort_t* xs = sm;               // reuse: [64][200] = 12800 ush (fits 14080)
  const int wm = wave >> 2, wn = wave & 3;

  for (int pass = 0; pass < 2; pass++){
    if (pass) __syncthreads();
    for (int c = tid; c < 1536; c += 512){
      int row = c / 24, t = c % 24;
      *reinterpret_cast<bf16x8*>(&xs[row*200 + t*8]) =
        *reinterpret_cast<const bf16x8*>(
          aoW + (((size_t)b*NH + (t>>2))*NTOK + pass*64 + row)*32 + (t&3)*8);
    }
    __syncthreads();

    f32x4 acc2[2][3];
    #pragma unroll
    for (int ct = 0; ct < 3; ct++){
      const int col = (wn*3 + ct)*16 + l16;
      float bfc = (col < DIMX) ? b_fc[col] : 0.f;
      acc2[0][ct] = f32x4{bfc, bfc, bfc, bfc};
      acc2[1][ct] = acc2[0][ct];
    }

    #pragma unroll
    for (int ks = 0; ks < 6; ks++){
      const int k0 = ks*32 + lq*8;
      bf16x8 a0 = *reinterpret_cast<const bf16x8*>(&xs[(wm*32 +      l16)*200 + k0]);
      bf16x8 a1 = *reinterpret_cast<const bf16x8*>(&xs[(wm*32 + 16 + l16)*200 + k0]);
      #pragma unroll
      for (int ct = 0; ct < 3; ct++){
        bf16x8 bw = *reinterpret_cast<const bf16x8*>(
            wfcP + ((size_t)((wn*3 + ct)*6 + ks)*64 + lane)*8);
        acc2[0][ct] = mfma16(a0, bw, acc2[0][ct]);
        acc2[1][ct] = mfma16(a1, bw, acc2[1][ct]);
      }
    }

    // epilogue: two 32-row half-passes through fp32 bounce (aliases xs)
    float* ob = reinterpret_cast<float*>(xs);   // [32][180] f32 per pass
    for (int hp = 0; hp < 2; hp++){
      __syncthreads();
      if (wm == hp){
        #pragma unroll
        for (int ct = 0; ct < 3; ct++){
          const int col = (wn*3 + ct)*16 + l16;
          if (col < DIMX){
            #pragma unroll
            for (int rt = 0; rt < 2; rt++)
              #pragma unroll
              for (int r = 0; r < 4; r++)
                ob[(rt*16 + lq*4 + r)*DIMX + col] = acc2[rt][ct][r];
          }
        }
      }
      __syncthreads();
      for (int c = tid; c < 1440; c += 512){
        int row = c / 45, cc = (c % 45)*4;
        float4 v = *reinterpret_cast<const float4*>(&ob[row*DIMX + cc]);
        *reinterpret_cast<float4*>(
            &out[((size_t)(b*2 + pass)*64 + hp*32 + row)*DIMX + cc]) = v;
      }
    }
  }
}

// ---------------- launch ----------------
extern "C" void kernel_launch(void* const* d_in, const int* in_sizes, int n_in,
                              void* d_out, int out_size, void* d_ws, size_t ws_size,
                              hipStream_t stream)
{
  const float* x      = (const float*)d_in[0];
  const float* w_qkv  = (const float*)d_in[1];
  const float* b_qkv  = (const float*)d_in[2];
  const float* w_fc   = (const float*)d_in[3];
  const float* b_fc   = (const float*)d_in[4];
  const float* rpt    = (const float*)d_in[5];
  const float* mask   = (const float*)d_in[6];
  const int*   rpi    = (const int*)d_in[7];
  float* out = (float*)d_out;

  char* ws = (char*)d_ws;
  // layout (bytes):
  //   0         wqkvP   216*64*8*2 = 221184
  //   221184    wfcP    72*64*8*2  = 73728
  //   294912    bias_p  12582912
  //   12877824  aoW     1024*6*128*32*2 = 50331648
  //   63209472  xbf     131072*192*2    = 50331648   -> total 113541120
  if (ws_size < (size_t)113541120) return;
  ushort_t* wqkvP  = (ushort_t*)(ws);
  ushort_t* wfcP   = (ushort_t*)(ws + 221184);
  ushort_t* bias_p = (ushort_t*)(ws + 294912);
  ushort_t* aoW    = (ushort_t*)(ws + 12877824);
  ushort_t* xbf    = (ushort_t*)(ws + 63209472);

  hipLaunchKernelGGL(prep_wqkv, dim3(216), dim3(64), 0, stream, w_qkv, wqkvP);
  hipLaunchKernelGGL(prep_wfc,  dim3(72),  dim3(64), 0, stream, w_fc, wfcP);
  hipLaunchKernelGGL(prep_bias, dim3(NWIN*NH*8), dim3(512), 0, stream, rpt, mask, rpi, bias_p);
  hipLaunchKernelGGL(prep_x,    dim3(6144), dim3(512), 0, stream, x, xbf);

  hipLaunchKernelGGL(fused_kernel, dim3(1024), dim3(512), 0, stream,
                     xbf, wqkvP, b_qkv, bias_p, aoW, wfcP, b_fc, out);
}

// Round 15
// 229.507 us; speedup vs baseline: 1.3212x; 1.3212x over previous
//
#include <hip/hip_runtime.h>

typedef unsigned short ushort_t;
typedef unsigned int uint32;
typedef __bf16 bf16x8 __attribute__((ext_vector_type(8)));
typedef float f32x4 __attribute__((ext_vector_type(4)));

#define NTOK 128
#define DIMX 180
#define NH 6
#define HD 30
#define NWIN 64
#define LOG2E 1.4426950408889634f
#define QSCALE (0.18257418583505536f * LOG2E)   // 1/sqrt(30) * log2(e)

// padded LDS strides (bank-conflict-free: 19, 70, 22 banks mod 32 all generate
// 16 distinct start banks across l16=0..15)
#define KS_STRIDE 38
#define VS_STRIDE 140
#define PW_STRIDE 44            // ush; 22 uints

__device__ __forceinline__ ushort_t f2bf(float f){
  uint32 u = __float_as_uint(f);
  u += 0x7FFFu + ((u >> 16) & 1u);
  return (ushort_t)(u >> 16);
}
__device__ __forceinline__ uint32 cvt_pk_bf16(float lo, float hi){
  uint32 r;
  asm("v_cvt_pk_bf16_f32 %0, %1, %2" : "=v"(r) : "v"(lo), "v"(hi));
  return r;
}
__device__ __forceinline__ f32x4 mfma16(bf16x8 a, bf16x8 b, f32x4 c){
  return __builtin_amdgcn_mfma_f32_16x16x32_bf16(a, b, c, 0, 0, 0);
}

// ---------------- prep kernels (r11/r12 verbatim) ----------------

// wqkvP fragment-contiguous: ((ct_g*6+ks)*64 + lane)*8 + e ; Q-segment pre-scaled
__global__ void prep_wqkv(const float* __restrict__ w, ushort_t* __restrict__ o){
  int blk = blockIdx.x;               // ct_g*6 + ks, 216 blocks
  int ct_g = blk / 6, ks = blk - ct_g*6;
  int lane = threadIdx.x;             // 64
  int l16 = lane & 15, lq = lane >> 4;
  int oc = ct_g*16 + l16;
  int seg = oc >> 5, dd = oc & 31;
  int sel = seg / NH, head = seg % NH;
  ushort_t vals[8];
  #pragma unroll
  for (int e = 0; e < 8; e++){
    int k = ks*32 + lq*8 + e;
    float v = 0.f;
    if (dd < HD && k < DIMX) v = w[k*(3*DIMX) + sel*DIMX + head*HD + dd];
    if (sel == 0) v *= QSCALE;
    vals[e] = f2bf(v);
  }
  *reinterpret_cast<uint4*>(&o[((size_t)blk*64 + lane)*8]) =
      *reinterpret_cast<const uint4*>(vals);
}

// wfcP fragment-contiguous; K positions pair-interleaved to match aoW layout:
// pos p in [0,32) holds original d = (p>>1) + (p&1)*16
__global__ void prep_wfc(const float* __restrict__ w, ushort_t* __restrict__ o){
  int blk = blockIdx.x;               // ct_g*6 + ks, 72 blocks
  int ct_g = blk / 6, ks = blk - ct_g*6;
  int lane = threadIdx.x;
  int l16 = lane & 15, lq = lane >> 4;
  int oc = ct_g*16 + l16;
  ushort_t vals[8];
  #pragma unroll
  for (int e = 0; e < 8; e++){
    int k = ks*32 + lq*8 + e;
    int hh = k >> 5, pos = k & 31;
    int d = (pos >> 1) + (pos & 1)*16;
    float v = (d < HD && oc < DIMX) ? w[(hh*HD + d)*DIMX + oc] : 0.f;
    vals[e] = f2bf(v);
  }
  *reinterpret_cast<uint4*>(&o[((size_t)blk*64 + lane)*8]) =
      *reinterpret_cast<const uint4*>(vals);
}

// bias_p in MFMA C-fragment order, pre-multiplied by log2(e)
__global__ void prep_bias(const float* __restrict__ rpt, const float* __restrict__ mask,
                          const int* __restrict__ rpi, ushort_t* __restrict__ o){
  int blk = blockIdx.x;            // (w*6+h)*8 + wave
  int wave = blk & 7, wh = blk >> 3;
  int h = wh % NH, w = wh / NH;
  int i = threadIdx.x;             // 512
  int lane = i >> 3, t = i & 7;
  int l16 = lane & 15, lq = lane >> 4;
  int m = t*16 + l16;
  ushort_t vals[4];
  #pragma unroll
  for (int r = 0; r < 4; r++){
    int n = wave*16 + lq*4 + r;
    float v = rpt[rpi[n*NTOK + m]*NH + h] + mask[((size_t)w*NTOK + n)*NTOK + m];
    vals[r] = f2bf(v * LOG2E);
  }
  *reinterpret_cast<uint2*>(&o[((size_t)blk*64 + lane)*32 + t*4]) =
      *reinterpret_cast<const uint2*>(vals);
}

// ---------------- fully fused: QKV + attention + FC, one block per window ----------------
// grid 1024, 512 thr, 8 waves x 16 token-rows each.
// LDS 66816 B: ws [2304*8]=18432 ush @0 (head-h weight slice; FC reuses as xs/ob);
//   k_s [128][38]=4864 @18432; v_s [32][140]=4480 @23296; p_s 8x[16][44]=5632 @27776.
// x lives in registers (xf[6] bf16x8 per wave). 2 blocks/CU (128-reg regime, no spill).
__global__ __launch_bounds__(512, 4) void fused_kernel(
    const float* __restrict__ x, const ushort_t* __restrict__ wqkvP,
    const float* __restrict__ b_qkv, const ushort_t* __restrict__ bias_p,
    ushort_t* __restrict__ aoW, const ushort_t* __restrict__ wfcP,
    const float* __restrict__ b_fc, float* __restrict__ out)
{
  __shared__ ushort_t sm[33408];
  ushort_t* ws  = sm;            // [6ct][6ks][64 lane][8]
  ushort_t* k_s = sm + 18432;    // [128 tok][38]
  ushort_t* v_s = sm + 23296;    // [32 d][140]  (token pos pair-interleaved)
  ushort_t* p_s = sm + 27776;    // 8 x [16][44]

  const int tid = threadIdx.x;
  const int b = blockIdx.x;
  const int wk = b & (NWIN-1);
  const int wave = tid >> 6, lane = tid & 63;
  const int l16 = lane & 15, lq = lane >> 4;
  const int wbase = wave * 16;
  ushort_t* pw = p_s + wave*704;
  uint32*   pwu = reinterpret_cast<uint32*>(pw);

  // ---- load this wave's 16 x-rows into bf16 register fragments (once) ----
  bf16x8 xf[6];
  {
    const float* xr = x + ((size_t)b*NTOK + wbase + l16)*DIMX;
    #pragma unroll
    for (int ks = 0; ks < 6; ks++){
      const int k0 = ks*32 + lq*8;
      float4 fa = {0.f,0.f,0.f,0.f}, fb = {0.f,0.f,0.f,0.f};
      if (k0 < DIMX)     fa = *reinterpret_cast<const float4*>(xr + k0);
      if (k0 + 4 < DIMX) fb = *reinterpret_cast<const float4*>(xr + k0 + 4);
      uint4 uu = { cvt_pk_bf16(fa.x, fa.y), cvt_pk_bf16(fa.z, fa.w),
                   cvt_pk_bf16(fb.x, fb.y), cvt_pk_bf16(fb.z, fb.w) };
      xf[ks] = *reinterpret_cast<bf16x8*>(&uu);
    }
  }

  for (int h = 0; h < NH; h++){
    // ---- stage head-h weight slice -> ws (coalesced) ----
    #pragma unroll
    for (int j = 0; j < 5; j++){
      int c = j*512 + tid;                 // (ct*6+ks)*64 + lane2, 2304 total
      if (c < 2304){
        int ct = c / 384, rem = c - ct*384;
        int ct_g = ((ct >> 1)*6 + h)*2 + (ct & 1);
        *reinterpret_cast<uint4*>(&ws[c*8]) =
            *reinterpret_cast<const uint4*>(&wqkvP[((size_t)ct_g*384 + rem)*8]);
      }
    }
    // QKV accumulators C-initialized with bias (Q pre-scaled)
    f32x4 acc[6];
    #pragma unroll
    for (int ct = 0; ct < 6; ct++){
      const int sel = ct >> 1;
      const int d = (ct & 1)*16 + l16;
      float bc = (d < HD) ? b_qkv[sel*DIMX + h*HD + d] : 0.f;
      if (sel == 0) bc *= QSCALE;
      acc[ct] = f32x4{bc, bc, bc, bc};
    }
    __syncthreads();   // ws ready; prev head's k_s/v_s/pw reads done

    // ---- QKV for head h: 16 rows x {Q,K,V}x32 per wave ----
    #pragma unroll
    for (int ks = 0; ks < 6; ks++){
      #pragma unroll
      for (int ct = 0; ct < 6; ct++){
        bf16x8 bw = *reinterpret_cast<const bf16x8*>(&ws[((ct*6 + ks)*64 + lane)*8]);
        acc[ct] = mfma16(xf[ks], bw, acc[ct]);
      }
    }

    // ---- epilogue: Q -> pw, K -> k_s, V -> v_s (interleaved token pos) ----
    #pragma unroll
    for (int hf = 0; hf < 2; hf++){
      const int d = hf*16 + l16;
      #pragma unroll
      for (int r = 0; r < 4; r++){
        const int tok = wbase + lq*4 + r;
        pw[(lq*4 + r)*PW_STRIDE + d] = f2bf(acc[0 + hf][r]);   // Q (own rows)
        k_s[tok*KS_STRIDE + d]       = f2bf(acc[2 + hf][r]);   // K
        const int tp = (tok & 96) + ((tok & 15) << 1) + ((tok >> 4) & 1);
        v_s[d*VS_STRIDE + tp]        = f2bf(acc[4 + hf][r]);   // V^T
      }
    }

    // bias fragment (latency hides under barrier + QK^T LDS reads)
    bf16x8 bb[4];
    {
      const ushort_t* bp = bias_p + (((size_t)(wk*NH + h)*8 + wave)*64 + lane)*32;
      #pragma unroll
      for (int c = 0; c < 4; c++) bb[c] = *reinterpret_cast<const bf16x8*>(bp + c*8);
    }
    __syncthreads();   // k_s, v_s visible to all waves

    // ---- QK^T with bias C-init ----
    bf16x8 aq = *reinterpret_cast<const bf16x8*>(&pw[l16*PW_STRIDE + lq*8]);
    f32x4 s[8];
    #pragma unroll
    for (int c = 0; c < 4; c++)
      #pragma unroll
      for (int r = 0; r < 4; r++){
        s[2*c][r]   = (float)bb[c][r];
        s[2*c+1][r] = (float)bb[c][4+r];
      }
    #pragma unroll
    for (int t = 0; t < 8; t++){
      bf16x8 bk = *reinterpret_cast<const bf16x8*>(&k_s[(t*16 + l16)*KS_STRIDE + lq*8]);
      s[t] = mfma16(aq, bk, s[t]);
    }

    // ---- softmax: exp2 direct, deferred normalization ----
    float inv[4];
    #pragma unroll
    for (int r = 0; r < 4; r++){
      float sum = 0.f;
      #pragma unroll
      for (int t = 0; t < 8; t++){
        float e = __builtin_exp2f(s[t][r]);
        s[t][r] = e; sum += e;
      }
      #pragma unroll
      for (int off = 1; off < 16; off <<= 1) sum += __shfl_xor(sum, off);
      inv[r] = __builtin_amdgcn_rcpf(sum);
    }

    // ---- PV in 4 k-quarters; P packed via cvt_pk (pair-interleaved tokens) ----
    f32x4 po[2] = { f32x4{0.f,0.f,0.f,0.f}, f32x4{0.f,0.f,0.f,0.f} };
    #pragma unroll
    for (int q = 0; q < 4; q++){
      #pragma unroll
      for (int r = 0; r < 4; r++)
        pwu[(lq*4 + r)*(PW_STRIDE/2) + l16] = cvt_pk_bf16(s[2*q][r], s[2*q+1][r]);
      bf16x8 ap = *reinterpret_cast<const bf16x8*>(&pw[l16*PW_STRIDE + lq*8]);
      #pragma unroll
      for (int ct = 0; ct < 2; ct++){
        bf16x8 bv = *reinterpret_cast<const bf16x8*>(
            &v_s[(ct*16 + l16)*VS_STRIDE + q*32 + lq*8]);
        po[ct] = mfma16(ap, bv, po[ct]);
      }
    }

    // normalize + pack po (d pair-interleaved) -> pw -> coalesced 1KB/wave store
    #pragma unroll
    for (int r = 0; r < 4; r++)
      pwu[(lq*4 + r)*(PW_STRIDE/2) + l16] = cvt_pk_bf16(po[0][r]*inv[r], po[1][r]*inv[r]);
    {
      bf16x8 vv = *reinterpret_cast<const bf16x8*>(
          &pw[(lane>>2)*PW_STRIDE + (lane&3)*8]);
      *reinterpret_cast<bf16x8*>(
        aoW + (((size_t)b*NH + h)*NTOK + wbase + (lane>>2))*32 + (lane&3)*8) = vv;
    }
  }

  // ---- phase 2: FC for this block's 128 rows (two 64-row passes) ----
  __syncthreads();                 // all LDS reads done; aoW stores drained
  ushort_t* xs = sm;               // reuse ws region: [64][200] = 12800 ush
  const int wm = wave >> 2, wn = wave & 3;

  for (int pass = 0; pass < 2; pass++){
    if (pass) __syncthreads();
    for (int c = tid; c < 1536; c += 512){
      int row = c / 24, t = c % 24;
      *reinterpret_cast<bf16x8*>(&xs[row*200 + t*8]) =
        *reinterpret_cast<const bf16x8*>(
          aoW + (((size_t)b*NH + (t>>2))*NTOK + pass*64 + row)*32 + (t&3)*8);
    }
    __syncthreads();

    f32x4 acc2[2][3];
    #pragma unroll
    for (int ct = 0; ct < 3; ct++){
      const int col = (wn*3 + ct)*16 + l16;
      float bfc = (col < DIMX) ? b_fc[col] : 0.f;
      acc2[0][ct] = f32x4{bfc, bfc, bfc, bfc};
      acc2[1][ct] = acc2[0][ct];
    }

    #pragma unroll
    for (int ks = 0; ks < 6; ks++){
      const int k0 = ks*32 + lq*8;
      bf16x8 a0 = *reinterpret_cast<const bf16x8*>(&xs[(wm*32 +      l16)*200 + k0]);
      bf16x8 a1 = *reinterpret_cast<const bf16x8*>(&xs[(wm*32 + 16 + l16)*200 + k0]);
      #pragma unroll
      for (int ct = 0; ct < 3; ct++){
        bf16x8 bw = *reinterpret_cast<const bf16x8*>(
            wfcP + ((size_t)((wn*3 + ct)*6 + ks)*64 + lane)*8);
        acc2[0][ct] = mfma16(a0, bw, acc2[0][ct]);
        acc2[1][ct] = mfma16(a1, bw, acc2[1][ct]);
      }
    }

    // epilogue: two 32-row half-passes through fp32 bounce (aliases xs)
    float* ob = reinterpret_cast<float*>(xs);   // [32][180] f32 per pass
    for (int hp = 0; hp < 2; hp++){
      __syncthreads();
      if (wm == hp){
        #pragma unroll
        for (int ct = 0; ct < 3; ct++){
          const int col = (wn*3 + ct)*16 + l16;
          if (col < DIMX){
            #pragma unroll
            for (int rt = 0; rt < 2; rt++)
              #pragma unroll
              for (int r = 0; r < 4; r++)
                ob[(rt*16 + lq*4 + r)*DIMX + col] = acc2[rt][ct][r];
          }
        }
      }
      __syncthreads();
      for (int c = tid; c < 1440; c += 512){
        int row = c / 45, cc = (c % 45)*4;
        float4 v = *reinterpret_cast<const float4*>(&ob[row*DIMX + cc]);
        *reinterpret_cast<float4*>(
            &out[((size_t)(b*2 + pass)*64 + hp*32 + row)*DIMX + cc]) = v;
      }
    }
  }
}

// ---------------- launch ----------------
extern "C" void kernel_launch(void* const* d_in, const int* in_sizes, int n_in,
                              void* d_out, int out_size, void* d_ws, size_t ws_size,
                              hipStream_t stream)
{
  const float* x      = (const float*)d_in[0];
  const float* w_qkv  = (const float*)d_in[1];
  const float* b_qkv  = (const float*)d_in[2];
  const float* w_fc   = (const float*)d_in[3];
  const float* b_fc   = (const float*)d_in[4];
  const float* rpt    = (const float*)d_in[5];
  const float* mask   = (const float*)d_in[6];
  const int*   rpi    = (const int*)d_in[7];
  float* out = (float*)d_out;

  char* ws = (char*)d_ws;
  // layout (bytes):
  //   0         wqkvP   216*64*8*2 = 221184
  //   221184    wfcP    72*64*8*2  = 73728
  //   294912    bias_p  12582912
  //   12877824  aoW     1024*6*128*32*2 = 50331648   -> total 63209472
  if (ws_size < (size_t)63209472) return;
  ushort_t* wqkvP  = (ushort_t*)(ws);
  ushort_t* wfcP   = (ushort_t*)(ws + 221184);
  ushort_t* bias_p = (ushort_t*)(ws + 294912);
  ushort_t* aoW    = (ushort_t*)(ws + 12877824);

  hipLaunchKernelGGL(prep_wqkv, dim3(216), dim3(64), 0, stream, w_qkv, wqkvP);
  hipLaunchKernelGGL(prep_wfc,  dim3(72),  dim3(64), 0, stream, w_fc, wfcP);
  hipLaunchKernelGGL(prep_bias, dim3(NWIN*NH*8), dim3(512), 0, stream, rpt, mask, rpi, bias_p);

  hipLaunchKernelGGL(fused_kernel, dim3(1024), dim3(512), 0, stream,
                     x, wqkvP, b_qkv, bias_p, aoW, wfcP, b_fc, out);
}